// Round 13
// baseline (98.319 us; speedup 1.0000x reference)
//
#include <hip/hip_runtime.h>
#include <hip/hip_bf16.h>

typedef __attribute__((ext_vector_type(4))) float f32x4;
typedef __attribute__((ext_vector_type(8))) short s16x8;
typedef __attribute__((ext_vector_type(4))) uint u32x4;

#define MFMA16(a, b, c) __builtin_amdgcn_mfma_f32_16x16x32_bf16(a, b, c, 0, 0, 0)

#define DG 256
#define NE 16
#define NN 17
#define TB 16      // tokens per block
#define NTOK 8192
#define PADU 264   // ushort row stride for bf16 LDS tiles (528 B, 16B-aligned, 2-way banks)

// ws offsets
#define WS_S    0        // Sdiv bf16 [17][256]  (ushort area, bytes 0..8704)
#define WS_AD   4376     // Ad2 dense [17*17] floats
#define WS_MSK  4704     // nonzero masks [16] (uint)
#define WS_EW   8768     // exp@W1 [16][256] floats
// ws byte offsets (pre-swizzled bf16 weight fragments, all single-bf16 now)
#define FB_WMH  65536
#define FB_W1H  1114112
#define FB_W2H  1376256
#define WS_NEED 1638400

// ---------- scalar RNE helper (setup + fallback only) ----------
__device__ __forceinline__ ushort bf16h(float f) {
    union { float f; uint u; } c; c.f = f;
    return (ushort)((c.u + 0x7fffu + ((c.u >> 16) & 1u)) >> 16);  // RNE
}

// ---------- fast packed converter (v_cvt_pk_bf16_f32) ----------
__device__ __forceinline__ uint pkbf(float a, float b) {
    __hip_bfloat162 t = __float22bfloat162_rn(make_float2(a, b));
    return *reinterpret_cast<uint*>(&t);
}

// W fragment: elem(l,i) = W[ks*32 + 8*(l>>4) + i][nt*16 + (l&15)]
template<bool SWZ>
__device__ __forceinline__ void loadBH(const ushort* __restrict__ H,
                                       const float* __restrict__ Wf,
                                       int KST, int nt, int ks, int lane,
                                       s16x8& bh) {
    if (SWZ) {
        bh = *(const s16x8*)(H + ((size_t)(nt * KST + ks) * 64 + lane) * 8);
    } else {
        const int k0 = ks * 32 + ((lane >> 4) << 3);
        const int col = nt * 16 + (lane & 15);
        const float* p = Wf + (size_t)k0 * DG + col;
#pragma unroll
        for (int i = 0; i < 8; ++i) bh[i] = (short)bf16h(p[(size_t)i * DG]);
    }
}

// -------- setup 1: blocks 0-15 expert path; blocks 16+ weight swizzle (all single bf16) --------
__global__ __launch_bounds__(512) void k_se1(const float* __restrict__ X,
                                             const float* __restrict__ Wst,
                                             const float* __restrict__ W1,
                                             const float* __restrict__ Wm,
                                             const float* __restrict__ W2,
                                             float* __restrict__ ws) {
    const int b = blockIdx.x, tid = threadIdx.x;
    if (b >= 16) {
        char* base = (char*)ws;
        const int base4 = (b - 16) * 2048 + tid * 4;
#pragma unroll
        for (int j = 0; j < 4; ++j) {
            const int local = base4 + j;
            const float* W; ushort* H; int lo2, KST;
            if (local < 262144)      { W = Wm; KST = 32; lo2 = local;          H = (ushort*)(base + FB_WMH); }
            else if (local < 327680) { W = W1; KST = 8;  lo2 = local - 262144; H = (ushort*)(base + FB_W1H); }
            else                     { W = W2; KST = 8;  lo2 = local - 327680; H = (ushort*)(base + FB_W2H); }
            const int i = lo2 & 7, l = (lo2 >> 3) & 63, t = lo2 >> 9;
            const int ks = t % KST, nt = t / KST;
            const int k = ks * 32 + ((l >> 4) << 3) + i;
            const int col = nt * 16 + (l & 15);
            H[lo2] = bf16h(W[(size_t)k * DG + col]);
        }
        return;
    }
    const int e = b;
    const int d = tid & 255, half = tid >> 8;
    __shared__ float xr[1024];
    __shared__ float part[2][256];
    __shared__ float er[256];

    *(float2*)&xr[tid * 2] = *(const float2*)&X[e * 1024 + tid * 2];
    __syncthreads();
    float acc = 0.f;
    const int k0 = half * 512;
    for (int k = 0; k < 512; ++k)
        acc = fmaf(xr[k0 + k], Wst[(size_t)(k0 + k) * DG + d], acc);
    part[half][d] = acc;
    __syncthreads();
    if (tid < 256) er[tid] = fmaxf(part[0][tid] + part[1][tid], 0.f);
    __syncthreads();
    float a2 = 0.f;
    const int m0 = half * 128;
    for (int m = 0; m < 128; ++m)
        a2 = fmaf(er[m0 + m], W1[(size_t)(m0 + m) * DG + d], a2);
    part[half][d] = a2;
    __syncthreads();
    if (tid < 256) ws[WS_EW + e * DG + tid] = part[0][tid] + part[1][tid];
}

// -------- setup 2 (18 blocks): 0-16 Sdiv rows (bf16); 17: Ad2 dense + nonzero masks --------
__global__ __launch_bounds__(256) void k_se2(const float* __restrict__ adj,
                                             float* __restrict__ ws) {
    const int b = blockIdx.x, tid = threadIdx.x;
    __shared__ float dinv[NN];
    __shared__ float row[NN];
    __shared__ float Ad_sh[NN * NN];
    if (tid < NN) {
        float deg = 0.f;
        for (int m = 0; m < NN; ++m) deg += adj[tid * NN + m];
        dinv[tid] = 1.0f / sqrtf(deg);
    }
    __syncthreads();
    if (b < NN) {
        if (tid < NN) row[tid] = adj[b * NN + tid] * dinv[b] * dinv[tid];
        __syncthreads();
        float s = 0.f;
        for (int e = 0; e < NE; ++e) s = fmaf(row[e], ws[WS_EW + e * DG + tid], s);
        const float ab = dinv[b] * dinv[16];   // a[b] > 0 (hub column all-ones)
        ((ushort*)ws)[b * 256 + tid] = bf16h(s / ab);
    } else {
        for (int i = tid; i < NN * NN; i += 256) {
            const int r = i / NN, c = i % NN;
            Ad_sh[i] = adj[i] * dinv[r] * dinv[c] * dinv[c] * dinv[16];
        }
        __syncthreads();
        for (int i = tid; i < NN * NN; i += 256) ws[WS_AD + i] = Ad_sh[i];
        if (tid < NE) {
            uint m = 0;
            for (int c = 0; c < NN; ++c)
                if (Ad_sh[tid * NN + c] != 0.f) m |= (1u << c);
            ((uint*)(ws))[WS_MSK + tid] = m;
        }
    }
}

// -------- fused main: TB=16, 1024 thr, 16 waves; A/B on 8 waves x 2 tiles; bf16 g/S LDS --------
template<bool SWZ>
__global__ __launch_bounds__(1024) void k_main(
        const float* __restrict__ x,
        const float* __restrict__ Wm,
        const float* __restrict__ W1,
        const float* __restrict__ W2,
        const float* __restrict__ Wp,
        const float* __restrict__ ws,
        float* __restrict__ out) {
    const int tid = threadIdx.x;
    const int lane = tid & 63, w = tid >> 6;          // wave = d-col-tile 0..15 (phase C/E)
    const int r16 = lane & 15, g4 = lane >> 4;
    const size_t t0 = (size_t)blockIdx.x * TB;

    __shared__ ushort S_bf[NN][PADU];                 // 8976 B (Sdiv bf16)
    __shared__ ushort g_bf[TB][PADU];                 // 8448 B (g bf16)
    __shared__ alignas(16) union {
        ushort xs[2][8][64][8];                       // 16384 B (x frags, dbuf)
        ushort hfH[8][64][8];                         // 8192 B (h frags, single bf16)
    } U1;
    __shared__ alignas(16) union {
        ushort frag[2][NN * 64 * 8];                  // 34816 B (y1 dbuf)
        float part[16][16][17];                       // 17408 B (aliases frag[0] only)
    } U2;
    __shared__ float Ad_l[NN * NN];

    // staging map: thread -> (row, 4-float segment) of the 16x256 x-chunk
    const int srow = tid >> 6;                        // 0..15
    const int sseg = tid & 63;
    const int sk8 = sseg >> 3;
    const int so  = (sseg * 4) & 31;
    const int sl  = ((so >> 3) << 4) | srow;
    const int si  = so & 7;                           // 0 or 4

    // load Sdiv (bf16 pairs) + Ad
    for (int j = tid; j < NN * 128; j += 1024)
        *(uint*)&S_bf[j >> 7][(j & 127) << 1] = ((const uint*)ws)[j];
    for (int j = tid; j < NN * NN; j += 1024) Ad_l[j] = ws[WS_AD + j];

    // hoist nonzero masks into SGPRs
    uint msk[NE];
#pragma unroll
    for (int e = 0; e < NE; ++e)
        msk[e] = __builtin_amdgcn_readfirstlane(((const uint*)ws)[WS_MSK + e]);

    const char* base = (const char*)ws;
    const ushort* WmH = (const ushort*)(base + FB_WMH);
    const ushort* W1H = (const ushort*)(base + FB_W1H);
    const ushort* W2H = (const ushort*)(base + FB_W2H);

    // stage x chunk 0 (single bf16, convert-once)
    {
        const f32x4 v = *(const f32x4*)&x[(t0 + srow) * 1024 + sseg * 4];
        uint2 uu = make_uint2(pkbf(v[0], v[1]), pkbf(v[2], v[3]));
        *(uint2*)&U1.xs[0][sk8][sl][si] = uu;
    }
    __syncthreads();

    // ---- phase A: h = relu(x @ Wm); 8 waves x 2 col-tiles; 4 chunks, dbuf ----
    f32x4 hacc[2];
    hacc[0] = (f32x4){0.f, 0.f, 0.f, 0.f};
    hacc[1] = (f32x4){0.f, 0.f, 0.f, 0.f};
    for (int c = 0; c < 4; ++c) {
        f32x4 xn;
        if (c < 3)
            xn = *(const f32x4*)&x[(t0 + srow) * 1024 + (c + 1) * 256 + sseg * 4];
        if (w < 8) {
            for (int k8 = 0; k8 < 8; ++k8) {
                s16x8 bh0, bh1;
                loadBH<SWZ>(WmH, Wm, 32, 2 * w,     c * 8 + k8, lane, bh0);
                loadBH<SWZ>(WmH, Wm, 32, 2 * w + 1, c * 8 + k8, lane, bh1);
                const s16x8 ah = *(const s16x8*)&U1.xs[c & 1][k8][lane][0];
                hacc[0] = MFMA16(ah, bh0, hacc[0]);
                hacc[1] = MFMA16(ah, bh1, hacc[1]);
            }
        }
        if (c < 3) {
            uint2 uu = make_uint2(pkbf(xn[0], xn[1]), pkbf(xn[2], xn[3]));
            *(uint2*)&U1.xs[(c + 1) & 1][sk8][sl][si] = uu;
        }
        __syncthreads();
    }

    // write h (relu, single bf16) as MFMA A-fragments (xs dead, post-barrier)
    if (w < 8) {
#pragma unroll
        for (int j = 0; j < 2; ++j) {
            const int c2 = 2 * w + j;
            const int k8h = c2 >> 1;                  // = w
            const int o = ((c2 & 1) << 4) | r16;
            const int lb = (o >> 3) << 4;
            const int ih = o & 7;
            const uint p01 = pkbf(fmaxf(hacc[j][0], 0.f), fmaxf(hacc[j][1], 0.f));
            const uint p23 = pkbf(fmaxf(hacc[j][2], 0.f), fmaxf(hacc[j][3], 0.f));
            const int r0 = g4 * 4;
            U1.hfH[k8h][lb + r0 + 0][ih] = (ushort)p01;
            U1.hfH[k8h][lb + r0 + 1][ih] = (ushort)(p01 >> 16);
            U1.hfH[k8h][lb + r0 + 2][ih] = (ushort)p23;
            U1.hfH[k8h][lb + r0 + 3][ih] = (ushort)(p23 >> 16);
        }
    }
    __syncthreads();

    // ---- phase B: g = h @ W1 (both single bf16); 8 waves x 2 tiles ----
    if (w < 8) {
        f32x4 gacc[2];
        gacc[0] = (f32x4){0.f, 0.f, 0.f, 0.f};
        gacc[1] = (f32x4){0.f, 0.f, 0.f, 0.f};
        for (int k8 = 0; k8 < 8; ++k8) {
            s16x8 bh0, bh1;
            loadBH<SWZ>(W1H, W1, 8, 2 * w,     k8, lane, bh0);
            loadBH<SWZ>(W1H, W1, 8, 2 * w + 1, k8, lane, bh1);
            const s16x8 ah = *(const s16x8*)&U1.hfH[k8][lane][0];
            gacc[0] = MFMA16(ah, bh0, gacc[0]);
            gacc[1] = MFMA16(ah, bh1, gacc[1]);
        }
#pragma unroll
        for (int j = 0; j < 2; ++j) {
            const uint q01 = pkbf(gacc[j][0], gacc[j][1]);
            const uint q23 = pkbf(gacc[j][2], gacc[j][3]);
            const int col = (2 * w + j) * 16 + r16;
            g_bf[g4 * 4 + 0][col] = (ushort)q01;
            g_bf[g4 * 4 + 1][col] = (ushort)(q01 >> 16);
            g_bf[g4 * 4 + 2][col] = (ushort)q23;
            g_bf[g4 * 4 + 3][col] = (ushort)(q23 >> 16);
        }
    }
    __syncthreads();   // g ready; hfH reads done (frag overlays U2 separately)

    // ---- phase C: layer-2 GEMM; y1 = relu(g + Sdiv[n]) built from bf16 LDS; dbuf, 1 barrier/ks ----
    f32x4 acc[NN];
#pragma unroll
    for (int n = 0; n < NN; ++n) acc[n] = (f32x4){0.f, 0.f, 0.f, 0.f};

    const int bl_ = tid & 63;
    const int bn_ = tid >> 6;
    const ushort* gB  = &g_bf[bl_ & 15][(bl_ >> 4) << 3];
    const ushort* sB0 = &S_bf[bn_][(bl_ >> 4) << 3];
    const ushort* sB1 = &S_bf[16][(bl_ >> 4) << 3];
    ushort* const fr0a = U2.frag[0] + (size_t)tid * 8;
    ushort* const fr1a = U2.frag[1] + (size_t)tid * 8;
    ushort* const fr0b = U2.frag[0] + (size_t)(tid + 1024) * 8;
    ushort* const fr1b = U2.frag[1] + (size_t)(tid + 1024) * 8;

    for (int ks = 0; ks < 8; ++ks) {
        s16x8 bh;
        loadBH<SWZ>(W2H, W2, 8, w, ks, lane, bh);

        const int ko = ks * 32;
        const u32x4 gU = *(const u32x4*)(gB + ko);
        {
            const u32x4 sU = *(const u32x4*)(sB0 + ko);
            u32x4 uu;
#pragma unroll
            for (int i = 0; i < 4; ++i) {
                union { uint u; float f; } gl, gh, sl2, sh;
                gl.u = gU[i] << 16;  gh.u = gU[i] & 0xffff0000u;
                sl2.u = sU[i] << 16; sh.u = sU[i] & 0xffff0000u;
                uu[i] = pkbf(fmaxf(gl.f + sl2.f, 0.f), fmaxf(gh.f + sh.f, 0.f));
            }
            *(u32x4*)((ks & 1) ? fr1a : fr0a) = uu;
        }
        if (tid < 64) {   // hub node 16 (shares gU)
            const u32x4 sU = *(const u32x4*)(sB1 + ko);
            u32x4 uu;
#pragma unroll
            for (int i = 0; i < 4; ++i) {
                union { uint u; float f; } gl, gh, sl2, sh;
                gl.u = gU[i] << 16;  gh.u = gU[i] & 0xffff0000u;
                sl2.u = sU[i] << 16; sh.u = sU[i] & 0xffff0000u;
                uu[i] = pkbf(fmaxf(gl.f + sl2.f, 0.f), fmaxf(gh.f + sh.f, 0.f));
            }
            *(u32x4*)((ks & 1) ? fr1b : fr0b) = uu;
        }
        __syncthreads();   // frag[ks&1] ready; dbuf makes one barrier/ks hazard-safe

        const ushort* fb = U2.frag[ks & 1];
        __builtin_amdgcn_s_setprio(1);
#pragma unroll
        for (int n = 0; n < NN; ++n) {
            const s16x8 ah = *(const s16x8*)&fb[(n * 64 + lane) * 8];
            acc[n] = MFMA16(ah, bh, acc[n]);
        }
        __builtin_amdgcn_s_setprio(0);
    }
    // last ks=7 reads frag[1]; part below aliases frag[0] only -> no hazard.

    // ---- phase E: y2 = relu(Ad2 @ z); score = y2 . Wp; masked scan + pair butterfly ----
    const float wp = Wp[w * 16 + r16];
    const bool b0 = (r16 & 1) != 0;
#pragma unroll
    for (int p = 0; p < 8; ++p) {
        f32x4 v2[2];
#pragma unroll
        for (int j = 0; j < 2; ++j) {
            const int e = 2 * p + j;
            f32x4 z = (f32x4){0.f, 0.f, 0.f, 0.f};
#pragma unroll
            for (int m = 0; m < NN; ++m) {
                if (msk[e] & (1u << m)) {          // SGPR test -> scalar branch
                    const float av = Ad_l[e * NN + m];
#pragma unroll
                    for (int r = 0; r < 4; ++r) z[r] = fmaf(av, acc[m][r], z[r]);
                }
            }
#pragma unroll
            for (int r = 0; r < 4; ++r) v2[j][r] = fmaxf(z[r], 0.f) * wp;
        }
        f32x4 wv;
#pragma unroll
        for (int r = 0; r < 4; ++r) {
            const float keep = b0 ? v2[1][r] : v2[0][r];
            const float send = b0 ? v2[0][r] : v2[1][r];
            wv[r] = keep + __shfl_xor(send, 1, 64);
        }
#pragma unroll
        for (int r = 0; r < 4; ++r) wv[r] += __shfl_xor(wv[r], 2, 64);
#pragma unroll
        for (int r = 0; r < 4; ++r) wv[r] += __shfl_xor(wv[r], 4, 64);
#pragma unroll
        for (int r = 0; r < 4; ++r) wv[r] += __shfl_xor(wv[r], 8, 64);
        if (r16 < 2)
#pragma unroll
            for (int r = 0; r < 4; ++r) U2.part[g4 * 4 + r][2 * p + r16][w] = wv[r];
    }
    __syncthreads();
    if (tid < 256) {
        const int t = tid >> 4, e = tid & 15;
        float s2 = 0.f;
#pragma unroll
        for (int q = 0; q < 16; ++q) s2 += U2.part[t][e][q];
        out[(t0 + t) * NE + e] = s2;
    }
}

extern "C" void kernel_launch(void* const* d_in, const int* in_sizes, int n_in,
                              void* d_out, int out_size, void* d_ws, size_t ws_size,
                              hipStream_t stream) {
    const float* x   = (const float*)d_in[0];
    const float* X   = (const float*)d_in[1];
    const float* Wm  = (const float*)d_in[2];
    const float* Wst = (const float*)d_in[3];
    const float* Wc  = (const float*)d_in[4];
    const float* Wp  = (const float*)d_in[5];
    const float* adj = (const float*)d_in[6];
    float* out = (float*)d_out;
    float* ws  = (float*)d_ws;
    const float* W1 = Wc;
    const float* W2 = Wc + DG * DG;

    if (ws_size >= (size_t)WS_NEED) {
        k_se1<<<16 + 192, 512, 0, stream>>>(X, Wst, W1, Wm, W2, ws);
        k_se2<<<18, 256, 0, stream>>>(adj, ws);
        k_main<true><<<NTOK / TB, 1024, 0, stream>>>(x, Wm, W1, W2, Wp, ws, out);
    } else {
        k_se1<<<16, 512, 0, stream>>>(X, Wst, W1, Wm, W2, ws);
        k_se2<<<18, 256, 0, stream>>>(adj, ws);
        k_main<false><<<NTOK / TB, 1024, 0, stream>>>(x, Wm, W1, W2, Wp, ws, out);
    }
}